// Round 12
// baseline (1484.663 us; speedup 1.0000x reference)
//
#include <hip/hip_runtime.h>

#define Hd 512
#define Bd 512
#define Vd 128
#define Sd 256

typedef _Float16 half8 __attribute__((ext_vector_type(8)));
typedef _Float16 half4v __attribute__((ext_vector_type(4)));
typedef float float4v __attribute__((ext_vector_type(4)));
typedef unsigned int uint4v __attribute__((ext_vector_type(4)));

__device__ __forceinline__ float sigf(float v) { return 1.0f / (1.0f + __expf(-v)); }
__device__ __forceinline__ float tanhfast(float v) { return 1.0f - 2.0f / (__expf(2.0f * v) + 1.0f); }

__device__ __forceinline__ void load_lds16(const void* g, void* l) {
  __builtin_amdgcn_global_load_lds(
      (const __attribute__((address_space(1))) unsigned int*)g,
      (__attribute__((address_space(3))) unsigned int*)l, 16, 0, 0);
}

#if __has_builtin(__builtin_amdgcn_raw_buffer_load_b128) && \
    __has_builtin(__builtin_amdgcn_make_buffer_rsrc)
#define USE_BUFLD 1
#else
#define USE_BUFLD 0
#endif

// Intra-XCD coherent 16B load: CPol=1 (sc0) bypasses L1, reads the XCD's L2.
// (OK for once-per-phase data reads; NOT for poll loops — r6/r8/r10 lesson:
// control plane must use real atomics.)
#if USE_BUFLD
__device__ __forceinline__ half8 load_frag(__amdgpu_buffer_rsrc_t rs,
                                           const _Float16* base, unsigned voff) {
  uint4v d = __builtin_amdgcn_raw_buffer_load_b128(rs, voff, 0, 1 /*sc0*/);
  union { uint4v u; half8 h; } cv; cv.u = d;
  return cv.h;
}
#else
typedef int __amdgpu_buffer_rsrc_t;
__device__ __forceinline__ half8 load_frag(__amdgpu_buffer_rsrc_t rs,
                                           const _Float16* base, unsigned voff) {
  (void)rs;
  const char* p = (const char*)base + voff;
  union { unsigned long long u[2]; half8 h; } cv;
  cv.u[0] = __hip_atomic_load((const unsigned long long*)p, __ATOMIC_RELAXED,
                              __HIP_MEMORY_SCOPE_AGENT);
  cv.u[1] = __hip_atomic_load((const unsigned long long*)(p + 8), __ATOMIC_RELAXED,
                              __HIP_MEMORY_SCOPE_AGENT);
  return cv.h;
}
#endif

// Plain h store: write-through L1 -> dirty in own-XCD L2, tracked by vmcnt.
__device__ __forceinline__ void storeh4(_Float16* base, unsigned voff, half4v v) {
  *(half4v*)((char*)base + voff) = v;
}

// wxt[dir][v][n] = Wx[g][k][v] + bx[g*H+k] + bh[g*H+k], n = (k<<2)|g. fp32.
__global__ __launch_bounds__(256) void prep_wxt(
    const float* __restrict__ WxF, const float* __restrict__ bxF, const float* __restrict__ bhF,
    const float* __restrict__ WxB, const float* __restrict__ bxB, const float* __restrict__ bhB,
    float* __restrict__ wxt) {
  int e = blockIdx.x * 256 + threadIdx.x;   // 0..524287
  int n = e & 2047;
  int v = (e >> 11) & 127;
  int dir = e >> 18;
  int k = n >> 2, g = n & 3;
  const float* Wx = dir ? WxB : WxF;
  const float* bx = dir ? bxB : bxF;
  const float* bh = dir ? bhB : bhF;
  int gk = g * Hd + k;
  wxt[e] = Wx[gk * Vd + v] + bx[gk] + bh[gk];
}

// whr[dir][n][hc] f16 = Wh_dir[g][k][hc], n = (k<<2)|g
__global__ __launch_bounds__(256) void prep_wh16(
    const float* __restrict__ WhF, const float* __restrict__ WhB, _Float16* __restrict__ whr) {
  int e = blockIdx.x * 256 + threadIdx.x;   // 0..2097151
  int hc = e & 511;
  int n = (e >> 9) & 2047;
  int dir = e >> 20;
  int k = n >> 2, g = n & 3;
  const float* Wh = dir ? WhB : WhF;
  whr[e] = (_Float16)Wh[(g * Hd + k) * Hd + hc];
}

// wfc16[dir][v][hc] f16 = Wfc[v][dir*512+hc]
__global__ __launch_bounds__(256) void prep_wfc16(
    const float* __restrict__ Wfc, _Float16* __restrict__ wfc16) {
  int e = blockIdx.x * 256 + threadIdx.x;   // 0..131071
  int hc = e & 511;
  int v = (e >> 9) & 127;
  int dir = e >> 16;
  wfc16[e] = (_Float16)Wfc[v * 1024 + dir * 512 + hc];
}

// xT[t][b] = x[b][t]
__global__ __launch_bounds__(256) void prep_xT(const int* __restrict__ x, int* __restrict__ xT) {
  int e = blockIdx.x * 256 + threadIdx.x;   // 0..131071
  int t = e >> 9, b = e & 511;
  xT[e] = x[b * Sd + t];
}

__global__ __launch_bounds__(256) void init_zero(float* __restrict__ p) {
  int e = blockIdx.x * 256 + threadIdx.x;
  float4 z; z.x = 0.f; z.y = 0.f; z.z = 0.f; z.w = 0.f;
  ((float4*)p)[e] = z;
}

__global__ __launch_bounds__(256) void init_out(const float* __restrict__ bfc,
                                                float* __restrict__ out) {
  int e = blockIdx.x * 256 + threadIdx.x;
  int v0 = (e & 31) * 4;
  ((float4*)out)[e] = *(const float4*)&bfc[v0];
}

// ---------------------------------------------------------------------------
// Persistent BiLSTM. 256 blocks x 512 threads, XCD-pinned groups.
// Self-org: xcd = s_getreg(HW_REG_XCC_ID); rank = atomicAdd(xcdctr[xcd]);
//   grp = xcd*2 + (rank>>4); nt = rank&15; dir = grp>>3; mt = grp&7.
// Wave w: ks = w>>2 (K half), wl = w&3 (m-quarter). B-frag register cache:
//   kc-local 0..3 x 8 ni in VGPRs, filled once (r9: bank conflicts halved).
// Barrier: publish = agent atomic store (tid 0, after drain barrier); release
//   = PER-WAVE poll of the 16 group flags with agent atomics, followed by an
//   asm memory clobber — REQUIRED: relaxed atomic polls do not order the
//   subsequent non-atomic h loads, and LLVM hoisted them above the poll in
//   r11 (stale h -> wrong values). The empty asm may-write all memory, so no
//   load can be hoisted above it; zero runtime cost.
// h layout (per phase-dir block, f16): byte(b,k) = (b>>4)*16384 + (k>>3)*256
//   + (b&15)*16 + (k&7)*2. 4 h phases; flag publish precedes FC.
// LDS: WhT [128][512] f16 xor-swizzled (131072 B) resident, GT [128][68] (17408 B).
#define SMEM_BYTES (131072 + 17408)

#define ISSUE2(D, C)                                                           \
  _Pragma("unroll") for (int j = 0; j < 2; ++j)                                \
      D[j] = load_frag(rs, hbuf, aoff + (unsigned)(((C) * 2 + j) * 1024));

// cached-B compute: kc-local (C)*2+j in [0,4) -> registers, no LDS
#define COMPUTE2C(D, C)                                                        \
  _Pragma("unroll") for (int j = 0; j < 2; ++j) {                              \
    _Pragma("unroll") for (int ni = 0; ni < 8; ++ni)                           \
      acc[ni] = __builtin_amdgcn_mfma_f32_16x16x32_f16(                        \
          D[j], bcache[(C) * 2 + j][ni], acc[ni], 0, 0, 0);                    \
  }

// LDS-B compute: kc-local (C)*2+j in [4,8)
#define COMPUTE2L(D, C)                                                        \
  _Pragma("unroll") for (int j = 0; j < 2; ++j) {                              \
    const int kcabs = ks * 8 + (C) * 2 + j;                                    \
    _Pragma("unroll") for (int ni = 0; ni < 8; ++ni) {                         \
      half8 bf = *(const half8*)((const char*)smem + brow[ni] +                \
                                 (((kcabs * 4 + kq) ^ bxor[ni]) * 16));        \
      acc[ni] = __builtin_amdgcn_mfma_f32_16x16x32_f16(D[j], bf, acc[ni], 0, 0, 0); \
    }                                                                          \
  }

#define FCC(D, C)                                                              \
  _Pragma("unroll") for (int j = 0; j < 2; ++j)                                \
      fa = __builtin_amdgcn_mfma_f32_16x16x32_f16(                             \
          D[j], *(const half8*)(Bfc + ((C) * 2 + j) * 32), fa, 0, 0, 0);

__global__ __launch_bounds__(512, 1) void bilstm_persist(
    const float* __restrict__ wxt, const int* __restrict__ xT,
    const _Float16* __restrict__ whr, const _Float16* __restrict__ wfc16,
    _Float16* __restrict__ hbuf, unsigned* __restrict__ flags,
    float* __restrict__ out) {
  extern __shared__ char smem[];
  _Float16* GT = (_Float16*)(smem + 131072);

  const int tid = threadIdx.x;
  const int lane = tid & 63;
  const int w = tid >> 6;         // 0..7
  const int ks = w >> 2;          // K-split half
  const int wl = w & 3;           // m-quarter (16 rows)

  // ---- self-organize: role from (physical XCD, rank-within-XCD) ----
  unsigned xcd;
  asm volatile("s_getreg_b32 %0, hwreg(HW_REG_XCC_ID)" : "=s"(xcd));
  xcd &= 7u;
  unsigned* xcdctr = flags + 8176;
  int* roleSh = (int*)GT;
  if (tid == 0) roleSh[0] = (int)atomicAdd(&xcdctr[xcd], 1u);
  __syncthreads();
  const int rank = roleSh[0];                // 0..31 (32 CUs/XCD, 1 block/CU)
  const int grp = (int)xcd * 2 + (rank >> 4);
  const int nt = rank & 15;
  const int dir = grp >> 3;
  const int mt = grp & 7;
  const int b0 = mt * 64;
  __syncthreads();                           // roleSh read done (GT reused later)

  // ---- prologue: Wh slice -> LDS, swizzled via pre-swizzled GLOBAL source ----
  {
    const char* wsrc = (const char*)(whr + ((size_t)(dir * 2048 + nt * 128)) * Hd);
#pragma unroll
    for (int i = 0; i < 16; ++i) {
      int e = i * 512 + tid;
      int n = e >> 6, cs = e & 63;
      load_lds16(wsrc + (size_t)n * 1024 + (size_t)(((cs ^ (n & 7)) * 16)),
                 (char*)smem + (size_t)e * 16);
    }
  }

  const int l15 = lane & 15;
  const int kq = lane >> 4;                 // 0..3

#if USE_BUFLD
  const __amdgpu_buffer_rsrc_t rs = __builtin_amdgcn_make_buffer_rsrc(
      (void*)hbuf, (short)0, (int)4194304, 0x00020000);
#else
  const __amdgpu_buffer_rsrc_t rs = 0;
#endif

  // A-fragment per-lane offset (phase-independent; wave owns 16 distinct rows)
  const unsigned aoff_lane = (unsigned)((b0 >> 4) + wl) * 16384u + kq * 256u +
                             l15 * 16u + (unsigned)ks * 8192u;

  int brow[8], bxor[8];
#pragma unroll
  for (int ni = 0; ni < 8; ++ni) {
    int n = ni * 16 + l15;
    brow[ni] = n * 1024;
    bxor[ni] = n & 7;
  }

  float creg[4];                             // c-state: 4 (b,k) pairs per thread
#pragma unroll
  for (int i = 0; i < 4; ++i) creg[i] = 0.f;

  const int bl = tid & 63;                   // epilogue: b within tile
  const int kh = tid >> 6;                   // epilogue: 4-k quad group (0..7)
  const int fcn = nt & 7;                    // FC v-tile
  const int gtm = wl * 16 + kq * 4;          // GT row base for this wave's lanes
  // epilogue h-store offset (phase-independent): k = nt*32 + kh*4 .. +4
  const unsigned soff_lane = (unsigned)(((b0 + bl) >> 4)) * 16384u +
                             (unsigned)(nt * 4 + (kh >> 1)) * 256u +
                             (unsigned)(bl & 15) * 16u + (unsigned)(kh & 1) * 8u;
  // per-wave poll target: lane < 16 watches group flag[lane]
  unsigned* pollflag = flags + (grp * 16 + l15) * 32;

  __syncthreads();                           // WhT ready (drains global_load_lds)

  // ---- B-fragment register cache: kc-local 0..3 x 8 ni (one-time LDS read) ----
  half8 bcache[4][8];
#pragma unroll
  for (int c = 0; c < 4; ++c) {
    const int kcabs = ks * 8 + c;
#pragma unroll
    for (int ni = 0; ni < 8; ++ni)
      bcache[c][ni] = *(const half8*)((const char*)smem + brow[ni] +
                                      (((kcabs * 4 + kq) ^ bxor[ni]) * 16));
  }

  for (int s = 0; s <= Sd; ++s) {
    const unsigned abase = (((unsigned)(s & 3)) * 2u + (unsigned)dir) * 524288u;
    const unsigned nbase = (((unsigned)(s + 1) & 3u) * 2u + (unsigned)dir) * 524288u;
    const unsigned aoff = abase + aoff_lane;

    half8 a0[2], a1[2], a2[2], a3[2];        // live through FC (register reuse)

    if (s < Sd) {
      float4v acc[8];
#pragma unroll
      for (int ni = 0; ni < 8; ++ni) acc[ni] = (float4v)0.f;

      ISSUE2(a0, 0)
      ISSUE2(a1, 1)
      ISSUE2(a2, 2)
      COMPUTE2C(a0, 0)                       // cached B: runs while a2/a3 in flight
      ISSUE2(a3, 3)
      COMPUTE2C(a1, 1)
      COMPUTE2L(a2, 2)
      COMPUTE2L(a3, 3)

      // epilogue operand prefetch (hidden under the GT barriers)
      const int t = dir ? (Sd - 1 - s) : s;
      const int b = b0 + bl;
      const int xv = xT[t * Bd + b];
      const float* wrow = wxt + ((size_t)(dir * Vd + xv)) * 2048 + nt * 128 + kh * 16;
      float4 wv[4];
#pragma unroll
      for (int kl = 0; kl < 4; ++kl) wv[kl] = *(const float4*)&wrow[kl * 4];

      // ---- K-split merge through GT ----
      if (ks == 1) {
#pragma unroll
        for (int ni = 0; ni < 8; ++ni) {
          int n = ni * 16 + l15;
          half4v hv4;
          hv4[0] = (_Float16)acc[ni][0];
          hv4[1] = (_Float16)acc[ni][1];
          hv4[2] = (_Float16)acc[ni][2];
          hv4[3] = (_Float16)acc[ni][3];
          *(half4v*)&GT[n * 68 + gtm] = hv4;
        }
      }
      __syncthreads();
      if (ks == 0) {
#pragma unroll
        for (int ni = 0; ni < 8; ++ni) {
          int n = ni * 16 + l15;
          half4v g4 = *(half4v*)&GT[n * 68 + gtm];
          half4v hv4;
          hv4[0] = (_Float16)(acc[ni][0] + (float)g4[0]);
          hv4[1] = (_Float16)(acc[ni][1] + (float)g4[1]);
          hv4[2] = (_Float16)(acc[ni][2] + (float)g4[2]);
          hv4[3] = (_Float16)(acc[ni][3] + (float)g4[3]);
          *(half4v*)&GT[n * 68 + gtm] = hv4;
        }
      }
      __syncthreads();

      // pointwise: thread (bl, kh) owns b = b0+bl, kloc = kh*4 .. +4
      half4v hv;
#pragma unroll
      for (int kl = 0; kl < 4; ++kl) {
        int kloc = kh * 4 + kl;
        float g0 = (float)GT[(kloc * 4 + 0) * 68 + bl] + wv[kl].x;
        float g1 = (float)GT[(kloc * 4 + 1) * 68 + bl] + wv[kl].y;
        float g2 = (float)GT[(kloc * 4 + 2) * 68 + bl] + wv[kl].z;
        float g3 = (float)GT[(kloc * 4 + 3) * 68 + bl] + wv[kl].w;
        float gi = sigf(g0), gf = sigf(g1), go = sigf(g2), gg = tanhfast(g3);
        float cn = gf * creg[kl] + gi * gg;
        creg[kl] = cn;
        hv[kl] = (_Float16)(go * tanhfast(cn));
      }
      storeh4(hbuf, nbase + soff_lane, hv);

      // Drain h-stores + finish GT reads (one barrier does both), then publish
      // EARLY with an agent atomic (un-hoistable, r7/r9-proven); barrier cost
      // overlaps with the FC below.
      __syncthreads();
      if (tid == 0)
        __hip_atomic_store(&flags[(grp * 16 + nt) * 32], (unsigned)(s + 1),
                           __ATOMIC_RELAXED, __HIP_MEMORY_SCOPE_AGENT);
    } else {
      // last iteration: K-loop skipped, but FC still needs the A-fragments.
      ISSUE2(a0, 0)
      ISSUE2(a1, 1)
      ISSUE2(a2, 2)
      ISSUE2(a3, 3)
    }

    // ---- FC of previous step's h: register-reuse of A-fragments, zero h loads.
    const bool fc_act = (s & 1) ? (nt < 8) : (nt >= 8);
    if (s > 0 && fc_act) {
      const _Float16* Bfc = wfc16 + (size_t)dir * (Vd * Hd) +
                            (size_t)(fcn * 16 + l15) * Hd + ks * 256 + kq * 8;
      float4v fa = (float4v)0.f;
      FCC(a0, 0)
      FCC(a1, 1)
      FCC(a2, 2)
      FCC(a3, 3)
      const int tf = dir ? (Sd - s) : (s - 1);
      const int v = fcn * 16 + l15;
      const int bb = b0 + wl * 16 + kq * 4;
      float* op = out + ((size_t)bb * Sd + tf) * Vd + v;
#pragma unroll
      for (int r2 = 0; r2 < 4; ++r2)
        unsafeAtomicAdd(op + (size_t)r2 * (Sd * Vd), fa[r2]);
    }

    if (s == Sd) break;

    // ---- group barrier: PER-WAVE self-release. Lanes 0..15 poll the 16
    // group flags with agent atomics (proven r5/r7/r9); wave continues when
    // all 16 lanes observe >= s+1. Early waves start next-step A-loads while
    // slow waves still poll.
    if (lane < 16) {
      while (__hip_atomic_load(pollflag, __ATOMIC_RELAXED,
                               __HIP_MEMORY_SCOPE_AGENT) < (unsigned)(s + 1))
        __builtin_amdgcn_s_sleep(1);
    }
    // Compiler fence: forbids hoisting next-step h loads above the poll
    // (r11's correctness failure). Zero runtime instructions.
    asm volatile("" ::: "memory");
  }
}

extern "C" void kernel_launch(void* const* d_in, const int* in_sizes, int n_in,
                              void* d_out, int out_size, void* d_ws, size_t ws_size,
                              hipStream_t stream) {
  (void)in_sizes; (void)n_in; (void)out_size; (void)ws_size;
  const int* x      = (const int*)d_in[0];
  const float* WxF  = (const float*)d_in[1];
  const float* WhF  = (const float*)d_in[2];
  const float* bxF  = (const float*)d_in[3];
  const float* bhF  = (const float*)d_in[4];
  const float* WxB  = (const float*)d_in[5];
  const float* WhB  = (const float*)d_in[6];
  const float* bxB  = (const float*)d_in[7];
  const float* bhB  = (const float*)d_in[8];
  const float* Wfc  = (const float*)d_in[9];
  const float* bfc  = (const float*)d_in[10];
  float* out = (float*)d_out;

  // ws (float units):
  //   wxt    @ 0        : 524288
  //   hbuf   @ 524288   : 1048576  (f16, 4 phases x 2 dir x 512 x 512)
  //   flags  @ 1572864  : 8192     (unsigned; [0..8159] flags, [8176..8183] xcdctr)
  //   wh16   @ 1581056  : 1048576  (f16, 2 dir x 2048 x 512)
  //   wfc16  @ 2629632  : 65536    (f16, 2 dir x 128 x 512)
  //   xT     @ 2695168  : 131072   (int, 256 x 512)
  float* ws = (float*)d_ws;
  float* wxt        = ws;
  _Float16* hbuf    = (_Float16*)(ws + 524288);
  unsigned* flags   = (unsigned*)(ws + 1572864);
  _Float16* wh16    = (_Float16*)(ws + 1581056);
  _Float16* wfc16   = (_Float16*)(ws + 2629632);
  int* xT           = (int*)(ws + 2695168);

  prep_wxt<<<2048, 256, 0, stream>>>(WxF, bxF, bhF, WxB, bxB, bhB, wxt);
  prep_wh16<<<8192, 256, 0, stream>>>(WhF, WhB, wh16);
  prep_wfc16<<<512, 256, 0, stream>>>(Wfc, wfc16);
  prep_xT<<<512, 256, 0, stream>>>(x, xT);
  init_zero<<<256, 256, 0, stream>>>(ws + 524288);    // h phase 0 (1 MB)
  init_zero<<<8, 256, 0, stream>>>(ws + 1572864);     // flags + xcdctr
  init_out<<<16384, 256, 0, stream>>>(bfc, out);

  static bool attr_set = false;
  if (!attr_set) {
    (void)hipFuncSetAttribute((const void*)bilstm_persist,
                              hipFuncAttributeMaxDynamicSharedMemorySize, SMEM_BYTES);
    attr_set = true;
  }
  void* kargs[] = {(void*)&wxt, (void*)&xT, (void*)&wh16, (void*)&wfc16,
                   (void*)&hbuf, (void*)&flags, (void*)&out};
  if (hipLaunchCooperativeKernel((const void*)bilstm_persist, dim3(256), dim3(512),
                                 kargs, SMEM_BYTES, stream) != hipSuccess) {
    // fallback: plain launch — 148 KB LDS forces 1 block/CU, 256 blocks on 256 CUs
    bilstm_persist<<<dim3(256), dim3(512), SMEM_BYTES, stream>>>(
        wxt, xT, wh16, wfc16, hbuf, flags, out);
  }
}